// Round 1
// baseline (167.885 us; speedup 1.0000x reference)
//
#include <hip/hip_runtime.h>
#include <math.h>

#define NQ 10
#define REGS 16   // amplitudes per lane: 64 lanes * 16 = 1024 = 2^10

// Coefficient layout in d_ws (float):
//   rot[L][q] : 8 floats (U00r,U00i,U01r,U01i,U10r,U10i,U11r,U11i) at (L*10+q)*8
//   cry[L][e] : 2 floats (cos(th/2), sin(th/2))                    at 160+(L*10+e)*2
// total 200 floats.

__global__ void precompute_coeffs(const float* __restrict__ w, float* __restrict__ coef) {
    if (threadIdx.x != 0 || blockIdx.x != 0) return;
    int wi = 0;
    for (int L = 0; L < 2; ++L) {
        for (int q = 0; q < NQ; ++q) {
            float phi = w[wi], theta = w[wi + 1], omega = w[wi + 2];
            wi += 3;
            float ct = cosf(0.5f * theta), st = sinf(0.5f * theta);
            float apo = 0.5f * (phi + omega);   // (phi+omega)/2
            float amo = 0.5f * (phi - omega);   // (phi-omega)/2
            float capo = cosf(apo), sapo = sinf(apo);
            float camo = cosf(amo), samo = sinf(amo);
            float* p = coef + (L * 10 + q) * 8;
            // U = RZ(omega)*RY(theta)*RZ(phi)
            p[0] =  capo * ct;  p[1] = -sapo * ct;   // U00 = ct*e^{-i(phi+omega)/2}
            p[2] = -camo * st;  p[3] = -samo * st;   // U01 = -st*e^{+i(phi-omega)/2}
            p[4] =  camo * st;  p[5] = -samo * st;   // U10 =  st*e^{-i(phi-omega)/2}
            p[6] =  capo * ct;  p[7] =  sapo * ct;   // U11 = ct*e^{+i(phi+omega)/2}
        }
        for (int e = 0; e < NQ; ++e) {
            float th = w[wi++];                      // FIXED_W is all-zero
            float* p = coef + 160 + (L * 10 + e) * 2;
            p[0] = cosf(0.5f * th);
            p[1] = sinf(0.5f * th);
        }
    }
}

__global__ __launch_bounds__(256) void qsim(const float* __restrict__ in,
                                            const float* __restrict__ coef,
                                            float* __restrict__ out, int B) {
    const int lane = threadIdx.x & 63;
    const int wave = threadIdx.x >> 6;
    const int b = blockIdx.x * 4 + wave;   // one wave per batch element
    if (b >= B) return;

    // ---- initial product state: ang = pi*clip(x,0,1); amp = prod (bit? sin : cos)(ang/2)
    float cc[NQ], ss[NQ];
#pragma unroll
    for (int q = 0; q < NQ; ++q) {
        float x = in[b * NQ + q];
        x = fminf(fmaxf(x, 0.0f), 1.0f);
        float a = 0.5f * 3.14159265358979323846f * x;  // (pi*x)/2
        cc[q] = cosf(a);
        ss[q] = sinf(a);
    }
    // lane bits 0..5 of index <-> qubits 9..4
    float lamp = 1.0f;
#pragma unroll
    for (int j = 0; j < 6; ++j) {
        lamp *= ((lane >> j) & 1) ? ss[9 - j] : cc[9 - j];
    }
    float sr[REGS], si[REGS];
#pragma unroll
    for (int r = 0; r < REGS; ++r) {
        float f = lamp;   // register bits 0..3 of r <-> qubits 3..0
#pragma unroll
        for (int j = 0; j < 4; ++j) f *= ((r >> j) & 1) ? ss[3 - j] : cc[3 - j];
        sr[r] = f;
        si[r] = 0.0f;
    }

    // ---- circuit: 2 x (U3 layer on all qubits, then ring CRY layer)
#pragma unroll
    for (int L = 0; L < 2; ++L) {
        // U3 rotations
#pragma unroll
        for (int q = 0; q < NQ; ++q) {
            const float* U = coef + (L * 10 + q) * 8;
            const float u00r = U[0], u00i = U[1], u01r = U[2], u01i = U[3];
            const float u10r = U[4], u10i = U[5], u11r = U[6], u11i = U[7];
            const int p = 9 - q;                  // bit position of qubit q
            if (p >= 6) {                         // in-register pair
                const int rb = p - 6;
#pragma unroll
                for (int r0 = 0; r0 < REGS; ++r0) {
                    if (r0 & (1 << rb)) continue;
                    const int r1 = r0 | (1 << rb);
                    const float a0r = sr[r0], a0i = si[r0];
                    const float a1r = sr[r1], a1i = si[r1];
                    sr[r0] = u00r * a0r - u00i * a0i + u01r * a1r - u01i * a1i;
                    si[r0] = u00r * a0i + u00i * a0r + u01r * a1i + u01i * a1r;
                    sr[r1] = u10r * a0r - u10i * a0i + u11r * a1r - u11i * a1i;
                    si[r1] = u10r * a0i + u10i * a0r + u11r * a1i + u11i * a1r;
                }
            } else {                              // cross-lane pair via shfl_xor
                const int mask = 1 << p;
                const bool hi = (lane >> p) & 1;
                const float dr = hi ? u11r : u00r, di = hi ? u11i : u00i;
                const float orr = hi ? u10r : u01r, oii = hi ? u10i : u01i;
#pragma unroll
                for (int r = 0; r < REGS; ++r) {
                    const float pr = __shfl_xor(sr[r], mask, 64);
                    const float pi_ = __shfl_xor(si[r], mask, 64);
                    const float mr = sr[r], mi = si[r];
                    sr[r] = dr * mr - di * mi + orr * pr - oii * pi_;
                    si[r] = dr * mi + di * mr + orr * pi_ + oii * pr;
                }
            }
        }
        // ring CRY entanglers: control u=e, target v=(e+1)%10
#pragma unroll
        for (int e = 0; e < NQ; ++e) {
            const float* C = coef + 160 + (L * 10 + e) * 2;
            const float c = C[0], s = C[1];
            const int u = e, v = (e + 1) % NQ;
            const int pc = 9 - u, pt = 9 - v;
            if (pt >= 6) {                        // in-register target
                const int rb = pt - 6;
#pragma unroll
                for (int r0 = 0; r0 < REGS; ++r0) {
                    if (r0 & (1 << rb)) continue;
                    const int r1 = r0 | (1 << rb);
                    const bool ctrl = (pc >= 6) ? (((r0 >> (pc - 6)) & 1) != 0)
                                                : (((lane >> pc) & 1) != 0);
                    const float a0r = sr[r0], a0i = si[r0];
                    const float a1r = sr[r1], a1i = si[r1];
                    const float n0r = c * a0r - s * a1r, n0i = c * a0i - s * a1i;
                    const float n1r = s * a0r + c * a1r, n1i = s * a0i + c * a1i;
                    if (ctrl) { sr[r0] = n0r; si[r0] = n0i; sr[r1] = n1r; si[r1] = n1i; }
                }
            } else {                              // cross-lane target; shuffles unconditional
                const int mask = 1 << pt;
                const bool hi = (lane >> pt) & 1;
                const float sgn = hi ? s : -s;
#pragma unroll
                for (int r = 0; r < REGS; ++r) {
                    const float pr = __shfl_xor(sr[r], mask, 64);
                    const float pi_ = __shfl_xor(si[r], mask, 64);
                    const bool ctrl = (pc >= 6) ? (((r >> (pc - 6)) & 1) != 0)
                                                : (((lane >> pc) & 1) != 0);
                    const float nr = c * sr[r] + sgn * pr;
                    const float ni = c * si[r] + sgn * pi_;
                    if (ctrl) { sr[r] = nr; si[r] = ni; }
                }
            }
        }
    }

    // ---- measure <Z_q> = sum_i |amp_i|^2 * (bit_q(i)==0 ? +1 : -1)
    float pb[REGS];
    float ptot = 0.0f;
#pragma unroll
    for (int r = 0; r < REGS; ++r) {
        pb[r] = sr[r] * sr[r] + si[r] * si[r];
        ptot += pb[r];
    }
    float z[NQ];
#pragma unroll
    for (int q = 0; q < 4; ++q) {                 // register-bit qubits
        const int rb = 3 - q;
        float acc = 0.0f;
#pragma unroll
        for (int r = 0; r < REGS; ++r) acc += ((r >> rb) & 1) ? -pb[r] : pb[r];
        z[q] = acc;
    }
#pragma unroll
    for (int q = 4; q < NQ; ++q) {                // lane-bit qubits
        const int p = 9 - q;
        z[q] = ((lane >> p) & 1) ? -ptot : ptot;
    }
    // wave-wide butterfly reduction of the 10 expectation values
#pragma unroll
    for (int q = 0; q < NQ; ++q) {
        float v = z[q];
#pragma unroll
        for (int off = 32; off; off >>= 1) v += __shfl_xor(v, off, 64);
        z[q] = v;
    }
    if (lane == 0) {
#pragma unroll
        for (int q = 0; q < NQ; ++q) out[b * NQ + q] = z[q];
    }
}

extern "C" void kernel_launch(void* const* d_in, const int* in_sizes, int n_in,
                              void* d_out, int out_size, void* d_ws, size_t ws_size,
                              hipStream_t stream) {
    const float* inputs  = (const float*)d_in[0];
    const float* weights = (const float*)d_in[1];
    float* out  = (float*)d_out;
    float* coef = (float*)d_ws;                   // 200 floats of scratch
    const int B = in_sizes[0] / NQ;               // 8192

    precompute_coeffs<<<1, 64, 0, stream>>>(weights, coef);
    qsim<<<(B + 3) / 4, 256, 0, stream>>>(inputs, coef, out, B);
}

// Round 2
// 129.596 us; speedup vs baseline: 1.2954x; 1.2954x over previous
//
#include <hip/hip_runtime.h>
#include <math.h>

#define NQ 10

typedef float v2f __attribute__((ext_vector_type(2)));

// Coefficient layout in d_ws (float):
//   rot[L][q] : 8 floats (U00r,U00i,U01r,U01i,U10r,U10i,U11r,U11i) at (L*10+q)*8
//   cry[L][e] : 2 floats (cos(th/2), sin(th/2))                    at 160+(L*10+e)*2
__global__ void precompute_coeffs(const float* __restrict__ w, float* __restrict__ coef) {
    const int t = threadIdx.x;
    if (t < 20) {                      // one U3 gate per thread
        const int L = t / 10, q = t % 10;
        const int wi = L * 40 + q * 3;
        float phi = w[wi], theta = w[wi + 1], omega = w[wi + 2];
        float ct = cosf(0.5f * theta), st = sinf(0.5f * theta);
        float apo = 0.5f * (phi + omega);
        float amo = 0.5f * (phi - omega);
        float capo = cosf(apo), sapo = sinf(apo);
        float camo = cosf(amo), samo = sinf(amo);
        float* p = coef + (L * 10 + q) * 8;
        p[0] =  capo * ct;  p[1] = -sapo * ct;   // U00
        p[2] = -camo * st;  p[3] = -samo * st;   // U01
        p[4] =  camo * st;  p[5] = -samo * st;   // U10
        p[6] =  capo * ct;  p[7] =  sapo * ct;   // U11
    } else if (t < 40) {               // one CRY per thread
        const int g = t - 20;
        const int L = g / 10, e = g % 10;
        const int wi = L * 40 + 30 + e;
        float th = w[wi];              // FIXED_W is all-zero
        float* p = coef + 160 + (L * 10 + e) * 2;
        p[0] = cosf(0.5f * th);
        p[1] = sinf(0.5f * th);
    }
}

// State layout per wave (one batch element per wave):
//   global index i[9:0], qubit q lives at bit p = 9-q.
//   lane = i[5:0]  (qubit q in 4..9  <-> lane bit 9-q)
//   k    = i[8:6]  (qubit 3 <-> k bit0, qubit 2 <-> k bit1, qubit 1 <-> k bit2)
//   j    = i[9]    (qubit 0) = vector component of v2f
// Sr[8], Si[8] of v2f: Sr[k] = { re(j=0,k,lane), re(j=1,k,lane) }

__device__ __forceinline__ v2f shflx(v2f v, int mask) {
    v2f r;
    r.x = __shfl_xor(v.x, mask, 64);
    r.y = __shfl_xor(v.y, mask, 64);
    return r;
}

// complex 2x2 on an in-k pair (components identical -> fully packed)
__device__ __forceinline__ void u3_pair(v2f& a0r, v2f& a0i, v2f& a1r, v2f& a1i,
                                        float u00r, float u00i, float u01r, float u01i,
                                        float u10r, float u10i, float u11r, float u11i) {
    v2f n0r = u00r * a0r - u00i * a0i + u01r * a1r - u01i * a1i;
    v2f n0i = u00r * a0i + u00i * a0r + u01r * a1i + u01i * a1r;
    v2f n1r = u10r * a0r - u10i * a0i + u11r * a1r - u11i * a1i;
    v2f n1i = u10r * a0i + u10i * a0r + u11r * a1i + u11i * a1r;
    a0r = n0r; a0i = n0i; a1r = n1r; a1i = n1i;
}

// real RY on an in-k pair (used by CRY where control is compile-time true)
__device__ __forceinline__ void ry_pair(v2f& a0r, v2f& a0i, v2f& a1r, v2f& a1i,
                                        float c, float s) {
    v2f n0r = c * a0r - s * a1r;
    v2f n0i = c * a0i - s * a1i;
    v2f n1r = s * a0r + c * a1r;
    v2f n1i = s * a0i + c * a1i;
    a0r = n0r; a0i = n0i; a1r = n1r; a1i = n1i;
}

__global__ __launch_bounds__(256) void qsim(const float* __restrict__ in,
                                            const float* __restrict__ coef,
                                            float* __restrict__ out, int B) {
    const int lane = threadIdx.x & 63;
    const int wave = threadIdx.x >> 6;
    const int b = blockIdx.x * 4 + wave;
    if (b >= B) return;

    // ---- initial product state
    float cc[NQ], ss[NQ];
#pragma unroll
    for (int q = 0; q < NQ; ++q) {
        float x = in[b * NQ + q];
        x = fminf(fmaxf(x, 0.0f), 1.0f);
        float a = 0.5f * 3.14159265358979323846f * x;
        cc[q] = cosf(a);
        ss[q] = sinf(a);
    }
    float lamp = 1.0f;
#pragma unroll
    for (int j = 0; j < 6; ++j) lamp *= ((lane >> j) & 1) ? ss[9 - j] : cc[9 - j];

    v2f Sr[8], Si[8];
    const v2f q0amp = {1.0f, 0.0f};   // placeholder overwritten below
    (void)q0amp;
#pragma unroll
    for (int k = 0; k < 8; ++k) {
        float f = lamp;
        f *= (k & 1) ? ss[3] : cc[3];
        f *= (k & 2) ? ss[2] : cc[2];
        f *= (k & 4) ? ss[1] : cc[1];
        v2f v; v.x = f * cc[0]; v.y = f * ss[0];
        Sr[k] = v;
        Si[k] = (v2f){0.0f, 0.0f};
    }

#pragma unroll
    for (int L = 0; L < 2; ++L) {
        // ================= U3 layer =================
        {   // q = 0 : component-bit gate (scalar within each v2f)
            const float* U = coef + (L * 10 + 0) * 8;
            const float u00r = U[0], u00i = U[1], u01r = U[2], u01i = U[3];
            const float u10r = U[4], u10i = U[5], u11r = U[6], u11i = U[7];
#pragma unroll
            for (int k = 0; k < 8; ++k) {
                const float a0r = Sr[k].x, a1r = Sr[k].y;
                const float a0i = Si[k].x, a1i = Si[k].y;
                const float n0r = u00r * a0r - u00i * a0i + u01r * a1r - u01i * a1i;
                const float n0i = u00r * a0i + u00i * a0r + u01r * a1i + u01i * a1r;
                const float n1r = u10r * a0r - u10i * a0i + u11r * a1r - u11i * a1i;
                const float n1i = u10r * a0i + u10i * a0r + u11r * a1i + u11i * a1r;
                Sr[k] = (v2f){n0r, n1r};
                Si[k] = (v2f){n0i, n1i};
            }
        }
        // q = 1,2,3 : k-bit gates, fully packed
#pragma unroll
        for (int q = 1; q <= 3; ++q) {
            const float* U = coef + (L * 10 + q) * 8;
            const float u00r = U[0], u00i = U[1], u01r = U[2], u01i = U[3];
            const float u10r = U[4], u10i = U[5], u11r = U[6], u11i = U[7];
            const int kb = (q == 1) ? 2 : (q == 2) ? 1 : 0;   // k-bit index
            const int step = 1 << kb;
#pragma unroll
            for (int k0 = 0; k0 < 8; ++k0) {
                if (k0 & step) continue;
                const int k1 = k0 | step;
                u3_pair(Sr[k0], Si[k0], Sr[k1], Si[k1],
                        u00r, u00i, u01r, u01i, u10r, u10i, u11r, u11i);
            }
        }
        // q = 4..9 : lane-bit gates (cross-lane), packed update
#pragma unroll
        for (int q = 4; q < NQ; ++q) {
            const float* U = coef + (L * 10 + q) * 8;
            const float u00r = U[0], u00i = U[1], u01r = U[2], u01i = U[3];
            const float u10r = U[4], u10i = U[5], u11r = U[6], u11i = U[7];
            const int p = 9 - q;
            const int mask = 1 << p;
            const bool hi = (lane >> p) & 1;
            const float dr = hi ? u11r : u00r, di = hi ? u11i : u00i;
            const float orr = hi ? u10r : u01r, oii = hi ? u10i : u01i;
#pragma unroll
            for (int k = 0; k < 8; ++k) {
                const v2f pr = shflx(Sr[k], mask);
                const v2f pi = shflx(Si[k], mask);
                const v2f mr = Sr[k], mi = Si[k];
                Sr[k] = dr * mr - di * mi + orr * pr - oii * pi;
                Si[k] = dr * mi + di * mr + orr * pi + oii * pr;
            }
        }

        // ================= CRY layer (ring) =================
        {   // e = 0 : ctrl = component bit (qubit0), tgt = qubit1 (k bit2)
            const float* C = coef + 160 + (L * 10 + 0) * 2;
            const v2f cv = {1.0f, C[0]};
            const v2f sv = {0.0f, C[1]};
#pragma unroll
            for (int k0 = 0; k0 < 4; ++k0) {
                const int k1 = k0 | 4;
                v2f n0r = cv * Sr[k0] - sv * Sr[k1];
                v2f n0i = cv * Si[k0] - sv * Si[k1];
                v2f n1r = sv * Sr[k0] + cv * Sr[k1];
                v2f n1i = sv * Si[k0] + cv * Si[k1];
                Sr[k0] = n0r; Si[k0] = n0i; Sr[k1] = n1r; Si[k1] = n1i;
            }
        }
        {   // e = 1 : ctrl = qubit1 (k bit2), tgt = qubit2 (k bit1): only k0 in {4,5}
            const float* C = coef + 160 + (L * 10 + 1) * 2;
            const float c = C[0], s = C[1];
            ry_pair(Sr[4], Si[4], Sr[6], Si[6], c, s);
            ry_pair(Sr[5], Si[5], Sr[7], Si[7], c, s);
        }
        {   // e = 2 : ctrl = qubit2 (k bit1), tgt = qubit3 (k bit0): only k0 in {2,6}
            const float* C = coef + 160 + (L * 10 + 2) * 2;
            const float c = C[0], s = C[1];
            ry_pair(Sr[2], Si[2], Sr[3], Si[3], c, s);
            ry_pair(Sr[6], Si[6], Sr[7], Si[7], c, s);
        }
        {   // e = 3 : ctrl = qubit3 (k bit0), tgt = qubit4 (lane bit5, mask 32)
            //         only odd k participate at all (compile-time control)
            const float* C = coef + 160 + (L * 10 + 3) * 2;
            const float c = C[0], s = C[1];
            const bool hi = (lane >> 5) & 1;
            const float sgn = hi ? s : -s;
#pragma unroll
            for (int k = 1; k < 8; k += 2) {
                const v2f pr = shflx(Sr[k], 32);
                const v2f pi = shflx(Si[k], 32);
                Sr[k] = c * Sr[k] + sgn * pr;
                Si[k] = c * Si[k] + sgn * pi;
            }
        }
        // e = 4..8 : ctrl = lane bit (6-(e-4)... i.e. bit 9-e), tgt = lane bit 8-e
#pragma unroll
        for (int e = 4; e <= 8; ++e) {
            const float* C = coef + 160 + (L * 10 + e) * 2;
            const float c = C[0], s = C[1];
            const int pc = 9 - e;          // control lane bit
            const int pt = 8 - e;          // target lane bit
            const int mask = 1 << pt;
            const bool ctrl = (lane >> pc) & 1;
            const float cl = ctrl ? c : 1.0f;
            const float sl = ctrl ? s : 0.0f;
            const bool hi = (lane >> pt) & 1;
            const float sgn = hi ? sl : -sl;
#pragma unroll
            for (int k = 0; k < 8; ++k) {
                const v2f pr = shflx(Sr[k], mask);
                const v2f pi = shflx(Si[k], mask);
                Sr[k] = cl * Sr[k] + sgn * pr;
                Si[k] = cl * Si[k] + sgn * pi;
            }
        }
        {   // e = 9 : ctrl = qubit9 (lane bit0), tgt = qubit0 (component bit)
            const float* C = coef + 160 + (L * 10 + 9) * 2;
            const bool ctrl = lane & 1;
            const float cl = ctrl ? C[0] : 1.0f;
            const float sl = ctrl ? C[1] : 0.0f;
#pragma unroll
            for (int k = 0; k < 8; ++k) {
                const float a0r = Sr[k].x, a1r = Sr[k].y;
                const float a0i = Si[k].x, a1i = Si[k].y;
                Sr[k] = (v2f){cl * a0r - sl * a1r, sl * a0r + cl * a1r};
                Si[k] = (v2f){cl * a0i - sl * a1i, sl * a0i + cl * a1i};
            }
        }
    }

    // ---- measurement: <Z_q> = P(bit_q=0) - P(bit_q=1)
    v2f P[8];
    float ptot = 0.0f;
#pragma unroll
    for (int k = 0; k < 8; ++k) {
        P[k] = Sr[k] * Sr[k] + Si[k] * Si[k];
        ptot += P[k].x + P[k].y;
    }
    float z[NQ];
    {   // qubit 0: component sign
        float acc = 0.0f;
#pragma unroll
        for (int k = 0; k < 8; ++k) acc += P[k].x - P[k].y;
        z[0] = acc;
    }
#pragma unroll
    for (int q = 1; q <= 3; ++q) {     // k-bit qubits
        const int kb = (q == 1) ? 2 : (q == 2) ? 1 : 0;
        float acc = 0.0f;
#pragma unroll
        for (int k = 0; k < 8; ++k) {
            const float pk = P[k].x + P[k].y;
            acc += ((k >> kb) & 1) ? -pk : pk;
        }
        z[q] = acc;
    }
#pragma unroll
    for (int q = 4; q < NQ; ++q) {     // lane-bit qubits
        const int p = 9 - q;
        z[q] = ((lane >> p) & 1) ? -ptot : ptot;
    }
    // wave-wide butterfly reduction
#pragma unroll
    for (int q = 0; q < NQ; ++q) {
        float v = z[q];
#pragma unroll
        for (int off = 32; off; off >>= 1) v += __shfl_xor(v, off, 64);
        z[q] = v;
    }
    if (lane == 0) {
#pragma unroll
        for (int q = 0; q < NQ; ++q) out[b * NQ + q] = z[q];
    }
}

extern "C" void kernel_launch(void* const* d_in, const int* in_sizes, int n_in,
                              void* d_out, int out_size, void* d_ws, size_t ws_size,
                              hipStream_t stream) {
    const float* inputs  = (const float*)d_in[0];
    const float* weights = (const float*)d_in[1];
    float* out  = (float*)d_out;
    float* coef = (float*)d_ws;
    const int B = in_sizes[0] / NQ;

    precompute_coeffs<<<1, 64, 0, stream>>>(weights, coef);
    qsim<<<(B + 3) / 4, 256, 0, stream>>>(inputs, coef, out, B);
}

// Round 3
// 96.656 us; speedup vs baseline: 1.7369x; 1.3408x over previous
//
#include <hip/hip_runtime.h>
#include <math.h>

#define NQ 10
typedef float v2f __attribute__((ext_vector_type(2)));

// read a float that lane `l` computed (result lands in an SGPR)
#define RL(v, l) __int_as_float(__builtin_amdgcn_readlane(__float_as_int(v), (l)))

template<int CTRL>
__device__ __forceinline__ float dppf(float x) {
    return __int_as_float(__builtin_amdgcn_update_dpp(
        __float_as_int(x), __float_as_int(x), CTRL, 0xF, 0xF, true));
}
template<int OFS>
__device__ __forceinline__ float swzf(float x) {
    return __int_as_float(__builtin_amdgcn_ds_swizzle(__float_as_int(x), OFS));
}
__device__ __forceinline__ float bperm(int idx, float x) {
    return __int_as_float(__builtin_amdgcn_ds_bpermute(idx, __float_as_int(x)));
}

// value held by lane (lane ^ (1<<P))
template<int P>
__device__ __forceinline__ float partner1(float x, int bpx32) {
    if constexpr (P == 0) return dppf<0xB1>(x);        // quad_perm [1,0,3,2] = xor1 (VALU)
    else if constexpr (P == 1) return dppf<0x4E>(x);   // quad_perm [2,3,0,1] = xor2 (VALU)
    else if constexpr (P == 2) return swzf<0x101F>(x); // ds_swizzle xor4
    else if constexpr (P == 3) return dppf<0x128>(x);  // row_ror:8 = xor8 (VALU)
    else if constexpr (P == 4) return swzf<0x401F>(x); // ds_swizzle xor16
    else return bperm(bpx32, x);                       // xor32 via ds_bpermute
}
template<int P>
__device__ __forceinline__ v2f partner2(v2f v, int bpx32) {
    v2f r;
    r.x = partner1<P>(v.x, bpx32);
    r.y = partner1<P>(v.y, bpx32);
    return r;
}

// complex 2x2 on an in-register pair (both v2f components identical role)
__device__ __forceinline__ void u3_pair(v2f& a0r, v2f& a0i, v2f& a1r, v2f& a1i,
                                        float u00r, float u00i, float u01r, float u01i,
                                        float u10r, float u10i, float u11r, float u11i) {
    v2f n0r = u00r * a0r - u00i * a0i + u01r * a1r - u01i * a1i;
    v2f n0i = u00r * a0i + u00i * a0r + u01r * a1i + u01i * a1r;
    v2f n1r = u10r * a0r - u10i * a0i + u11r * a1r - u11i * a1i;
    v2f n1i = u10r * a0i + u10i * a0r + u11r * a1i + u11i * a1r;
    a0r = n0r; a0i = n0i; a1r = n1r; a1i = n1i;
}
__device__ __forceinline__ void ry_pair(v2f& a0r, v2f& a0i, v2f& a1r, v2f& a1i,
                                        float c, float s) {
    v2f n0r = c * a0r - s * a1r;
    v2f n0i = c * a0i - s * a1i;
    v2f n1r = s * a0r + c * a1r;
    v2f n1i = s * a0i + c * a1i;
    a0r = n0r; a0i = n0i; a1r = n1r; a1i = n1i;
}

// U3 gate on lane-bit P
template<int P>
__device__ __forceinline__ void u3_lane(v2f (&Sr)[8], v2f (&Si)[8], int lane, int bpx32,
                                        float u00r, float u00i, float u01r, float u01i,
                                        float u10r, float u10i, float u11r, float u11i) {
    const bool hi = (lane >> P) & 1;
    const float dr = hi ? u11r : u00r, di = hi ? u11i : u00i;
    const float orr = hi ? u10r : u01r, oii = hi ? u10i : u01i;
#pragma unroll
    for (int k = 0; k < 8; ++k) {
        const v2f mr = Sr[k], mi = Si[k];
        const v2f pr = partner2<P>(mr, bpx32);
        const v2f pi = partner2<P>(mi, bpx32);
        Sr[k] = dr * mr - di * mi + orr * pr - oii * pi;
        Si[k] = dr * mi + di * mr + orr * pi + oii * pr;
    }
}

// CRY with control on lane-bit PC, target on lane-bit PT
template<int PC, int PT>
__device__ __forceinline__ void cry_lane(v2f (&Sr)[8], v2f (&Si)[8], int lane, int bpx32,
                                         float c, float s) {
    const bool ctrl = (lane >> PC) & 1;
    const float cl = ctrl ? c : 1.0f;
    const float sl = ctrl ? s : 0.0f;
    const bool hi = (lane >> PT) & 1;
    const float sgn = hi ? sl : -sl;
#pragma unroll
    for (int k = 0; k < 8; ++k) {
        const v2f pr = partner2<PT>(Sr[k], bpx32);
        const v2f pi = partner2<PT>(Si[k], bpx32);
        Sr[k] = cl * Sr[k] + sgn * pr;
        Si[k] = cl * Si[k] + sgn * pi;
    }
}

__device__ __forceinline__ float wave_sum(float x, int bpx32) {
    x += dppf<0xB1>(x);
    x += dppf<0x4E>(x);
    x += swzf<0x101F>(x);
    x += dppf<0x128>(x);
    x += swzf<0x401F>(x);
    x += bperm(bpx32, x);
    return x;
}

// State layout per wave (one batch element per wave):
//   global index i[9:0], qubit q lives at bit p = 9-q.
//   lane = i[5:0] (qubit 4..9 <-> lane bit 9-q), k = i[8:6] (qubits 3,2,1), comp j = i9 (qubit 0)
__global__ __launch_bounds__(256) void qsim(const float* __restrict__ in,
                                            const float* __restrict__ w,
                                            float* __restrict__ out, int B) {
    const int lane = threadIdx.x & 63;
    const int wave = threadIdx.x >> 6;
    int b = blockIdx.x * 4 + wave;
    b = __builtin_amdgcn_readfirstlane(b);   // force scalar loads for wave-uniform reads
    if (b >= B) return;
    const int bpx32 = (lane ^ 32) << 2;      // bpermute byte-index for xor32

    // ---- distributed coefficient generation (one gate per lane) ----
    // lanes 0..19:  U3 gate g (L=g/10, q=g%10) -> c0..c7 = U00r,U00i,U01r,U01i,U10r,U10i,U11r,U11i
    // lanes 20..39: CRY gate  -> c0 = cos(th/2), c1 = sin(th/2)
    // lanes 40..49: input q=lane-40 -> c0 = cos(pi*x/2), c1 = sin(pi*x/2)
    float ang0 = 0.0f, ang1 = 0.0f, ang2 = 0.0f;
    if (lane < 20) {
        const int L = lane / 10, q = lane - L * 10;
        const int wi = L * 40 + q * 3;
        const float phi = w[wi], theta = w[wi + 1], omega = w[wi + 2];
        ang0 = 0.5f * theta;
        ang1 = 0.5f * (phi + omega);
        ang2 = 0.5f * (phi - omega);
    } else if (lane < 40) {
        const int g = lane - 20;
        const int L = g / 10, e = g - L * 10;
        ang0 = 0.5f * w[L * 40 + 30 + e];          // FIXED_W is all-zero
    } else if (lane < 50) {
        float x = in[b * NQ + (lane - 40)];
        x = fminf(fmaxf(x, 0.0f), 1.0f);
        ang0 = 0.5f * 3.14159265358979323846f * x;
    }
    const float ca = __cosf(ang0), sa = __sinf(ang0);
    const float cb = __cosf(ang1), sb = __sinf(ang1);
    const float cg = __cosf(ang2), sg = __sinf(ang2);
    float c0, c1, c2, c3, c4, c5, c6, c7;
    c0 =  ca * cb;  c1 = -ca * sb;   // U00
    c2 = -sa * cg;  c3 = -sa * sg;   // U01
    c4 =  sa * cg;  c5 = -sa * sg;   // U10
    c6 =  ca * cb;  c7 =  ca * sb;   // U11
    if (lane >= 20) { c0 = ca; c1 = sa; }   // CRY / input lanes: plain cos,sin

#define U3C(L, q) \
    const float u00r = RL(c0, (L)*10+(q)), u00i = RL(c1, (L)*10+(q)), \
                u01r = RL(c2, (L)*10+(q)), u01i = RL(c3, (L)*10+(q)), \
                u10r = RL(c4, (L)*10+(q)), u10i = RL(c5, (L)*10+(q)), \
                u11r = RL(c6, (L)*10+(q)), u11i = RL(c7, (L)*10+(q));
#define CRYC(L, e) \
    const float c = RL(c0, 20+(L)*10+(e)), s = RL(c1, 20+(L)*10+(e));

    // ---- initial product state ----
    float cc[NQ], ss[NQ];
#pragma unroll
    for (int q = 0; q < NQ; ++q) { cc[q] = RL(c0, 40 + q); ss[q] = RL(c1, 40 + q); }
    float lamp = 1.0f;
#pragma unroll
    for (int j = 0; j < 6; ++j) lamp *= ((lane >> j) & 1) ? ss[9 - j] : cc[9 - j];

    v2f Sr[8], Si[8];
#pragma unroll
    for (int k = 0; k < 8; ++k) {
        float f = lamp;
        f *= (k & 1) ? ss[3] : cc[3];
        f *= (k & 2) ? ss[2] : cc[2];
        f *= (k & 4) ? ss[1] : cc[1];
        Sr[k] = (v2f){f * cc[0], f * ss[0]};
        Si[k] = (v2f){0.0f, 0.0f};
    }

#pragma unroll
    for (int L = 0; L < 2; ++L) {
        // ================= U3 layer =================
        {   // q = 0 : component-bit gate, packed via .yx swizzle
            U3C(L, 0);
            const v2f Dr = {u00r, u11r}, Di = {u00i, u11i};
            const v2f Or = {u01r, u10r}, Oi = {u01i, u10i};
#pragma unroll
            for (int k = 0; k < 8; ++k) {
                const v2f Ar = Sr[k], Ai = Si[k];
                const v2f Br = Ar.yx, Bi = Ai.yx;
                Sr[k] = Dr * Ar - Di * Ai + Or * Br - Oi * Bi;
                Si[k] = Dr * Ai + Di * Ar + Or * Bi + Oi * Br;
            }
        }
        // q = 1,2,3 : k-bit gates
#pragma unroll
        for (int q = 1; q <= 3; ++q) {
            U3C(L, q);
            const int kb = (q == 1) ? 2 : (q == 2) ? 1 : 0;
            const int step = 1 << kb;
#pragma unroll
            for (int k0 = 0; k0 < 8; ++k0) {
                if (k0 & step) continue;
                const int k1 = k0 | step;
                u3_pair(Sr[k0], Si[k0], Sr[k1], Si[k1],
                        u00r, u00i, u01r, u01i, u10r, u10i, u11r, u11i);
            }
        }
        // q = 4..9 : lane-bit gates (P = 9-q)
        { U3C(L, 4); u3_lane<5>(Sr, Si, lane, bpx32, u00r,u00i,u01r,u01i,u10r,u10i,u11r,u11i); }
        { U3C(L, 5); u3_lane<4>(Sr, Si, lane, bpx32, u00r,u00i,u01r,u01i,u10r,u10i,u11r,u11i); }
        { U3C(L, 6); u3_lane<3>(Sr, Si, lane, bpx32, u00r,u00i,u01r,u01i,u10r,u10i,u11r,u11i); }
        { U3C(L, 7); u3_lane<2>(Sr, Si, lane, bpx32, u00r,u00i,u01r,u01i,u10r,u10i,u11r,u11i); }
        { U3C(L, 8); u3_lane<1>(Sr, Si, lane, bpx32, u00r,u00i,u01r,u01i,u10r,u10i,u11r,u11i); }
        { U3C(L, 9); u3_lane<0>(Sr, Si, lane, bpx32, u00r,u00i,u01r,u01i,u10r,u10i,u11r,u11i); }

        // ================= CRY ring =================
        {   // e = 0 : ctrl = component bit (q0), tgt = q1 (k bit2)
            CRYC(L, 0);
            const v2f cv = {1.0f, c};
            const v2f sv = {0.0f, s};
#pragma unroll
            for (int k0 = 0; k0 < 4; ++k0) {
                const int k1 = k0 | 4;
                v2f n0r = cv * Sr[k0] - sv * Sr[k1];
                v2f n0i = cv * Si[k0] - sv * Si[k1];
                v2f n1r = sv * Sr[k0] + cv * Sr[k1];
                v2f n1i = sv * Si[k0] + cv * Si[k1];
                Sr[k0] = n0r; Si[k0] = n0i; Sr[k1] = n1r; Si[k1] = n1i;
            }
        }
        {   // e = 1 : ctrl = q1 (k bit2), tgt = q2 (k bit1)
            CRYC(L, 1);
            ry_pair(Sr[4], Si[4], Sr[6], Si[6], c, s);
            ry_pair(Sr[5], Si[5], Sr[7], Si[7], c, s);
        }
        {   // e = 2 : ctrl = q2 (k bit1), tgt = q3 (k bit0)
            CRYC(L, 2);
            ry_pair(Sr[2], Si[2], Sr[3], Si[3], c, s);
            ry_pair(Sr[6], Si[6], Sr[7], Si[7], c, s);
        }
        {   // e = 3 : ctrl = q3 (k bit0), tgt = q4 (lane bit5): only odd k
            CRYC(L, 3);
            const bool hi = (lane >> 5) & 1;
            const float sgn = hi ? s : -s;
#pragma unroll
            for (int k = 1; k < 8; k += 2) {
                const v2f pr = partner2<5>(Sr[k], bpx32);
                const v2f pi = partner2<5>(Si[k], bpx32);
                Sr[k] = c * Sr[k] + sgn * pr;
                Si[k] = c * Si[k] + sgn * pi;
            }
        }
        { CRYC(L, 4); cry_lane<5, 4>(Sr, Si, lane, bpx32, c, s); }   // q4 -> q5
        { CRYC(L, 5); cry_lane<4, 3>(Sr, Si, lane, bpx32, c, s); }   // q5 -> q6
        { CRYC(L, 6); cry_lane<3, 2>(Sr, Si, lane, bpx32, c, s); }   // q6 -> q7
        { CRYC(L, 7); cry_lane<2, 1>(Sr, Si, lane, bpx32, c, s); }   // q7 -> q8
        { CRYC(L, 8); cry_lane<1, 0>(Sr, Si, lane, bpx32, c, s); }   // q8 -> q9
        {   // e = 9 : ctrl = q9 (lane bit0), tgt = q0 (component bit)
            CRYC(L, 9);
            const bool ctrl = lane & 1;
            const float cl = ctrl ? c : 1.0f;
            const float sl = ctrl ? s : 0.0f;
            const v2f C2 = {cl, cl};
            const v2f S2 = {-sl, sl};
#pragma unroll
            for (int k = 0; k < 8; ++k) {
                const v2f Ar = Sr[k], Ai = Si[k];
                Sr[k] = C2 * Ar + S2 * Ar.yx;
                Si[k] = C2 * Ai + S2 * Ai.yx;
            }
        }
    }

    // ---- measurement ----
    v2f P[8];
    float ptot = 0.0f;
#pragma unroll
    for (int k = 0; k < 8; ++k) {
        P[k] = Sr[k] * Sr[k] + Si[k] * Si[k];
        ptot += P[k].x + P[k].y;
    }
    float z[NQ];
    {
        float acc = 0.0f;
#pragma unroll
        for (int k = 0; k < 8; ++k) acc += P[k].x - P[k].y;
        z[0] = acc;
    }
#pragma unroll
    for (int q = 1; q <= 3; ++q) {
        const int kb = (q == 1) ? 2 : (q == 2) ? 1 : 0;
        float acc = 0.0f;
#pragma unroll
        for (int k = 0; k < 8; ++k) {
            const float pk = P[k].x + P[k].y;
            acc += ((k >> kb) & 1) ? -pk : pk;
        }
        z[q] = acc;
    }
#pragma unroll
    for (int q = 4; q < NQ; ++q) {
        const int p = 9 - q;
        z[q] = ((lane >> p) & 1) ? -ptot : ptot;
    }
#pragma unroll
    for (int q = 0; q < NQ; ++q) z[q] = wave_sum(z[q], bpx32);

    if (lane == 0) {
#pragma unroll
        for (int q = 0; q < NQ; ++q) out[b * NQ + q] = z[q];
    }
}

extern "C" void kernel_launch(void* const* d_in, const int* in_sizes, int n_in,
                              void* d_out, int out_size, void* d_ws, size_t ws_size,
                              hipStream_t stream) {
    const float* inputs  = (const float*)d_in[0];
    const float* weights = (const float*)d_in[1];
    float* out = (float*)d_out;
    const int B = in_sizes[0] / NQ;

    qsim<<<(B + 3) / 4, 256, 0, stream>>>(inputs, weights, out, B);
}

// Round 4
// 83.436 us; speedup vs baseline: 2.0121x; 1.1584x over previous
//
#include <hip/hip_runtime.h>
#include <math.h>

#define NQ 10
typedef float v2f __attribute__((ext_vector_type(2)));

// read a float computed by lane `l` (lands in an SGPR; wave-uniform)
#define RL(v, l) __int_as_float(__builtin_amdgcn_readlane(__float_as_int(v), (l)))

template<int CTRL>
__device__ __forceinline__ float dppf(float x) {
    return __int_as_float(__builtin_amdgcn_update_dpp(
        __float_as_int(x), __float_as_int(x), CTRL, 0xF, 0xF, true));
}
template<int OFS>
__device__ __forceinline__ float swzf(float x) {
    return __int_as_float(__builtin_amdgcn_ds_swizzle(__float_as_int(x), OFS));
}
__device__ __forceinline__ float bperm(int idx, float x) {
    return __int_as_float(__builtin_amdgcn_ds_bpermute(idx, __float_as_int(x)));
}

// value held by lane (lane ^ (1<<P))
template<int P>
__device__ __forceinline__ float partner1(float x, int bpx32) {
    if constexpr (P == 0) return dppf<0xB1>(x);        // quad_perm xor1 (VALU)
    else if constexpr (P == 1) return dppf<0x4E>(x);   // quad_perm xor2 (VALU)
    else if constexpr (P == 2) return swzf<0x101F>(x); // ds_swizzle xor4
    else if constexpr (P == 3) return dppf<0x128>(x);  // row_ror:8 = xor8 (VALU)
    else if constexpr (P == 4) return swzf<0x401F>(x); // ds_swizzle xor16
    else return bperm(bpx32, x);                       // xor32 via ds_bpermute
}
template<int P>
__device__ __forceinline__ v2f partner2(v2f v, int bpx32) {
    v2f r;
    r.x = partner1<P>(v.x, bpx32);
    r.y = partner1<P>(v.y, bpx32);
    return r;
}

struct CMat { float m00r,m00i,m01r,m01i,m10r,m10i,m11r,m11i; };

#define RLMAT(name, l) const CMat name = { RL(c0,(l)), RL(c1,(l)), RL(c2,(l)), RL(c3,(l)), \
                                           RL(c4,(l)), RL(c5,(l)), RL(c6,(l)), RL(c7,(l)) };

// full complex 2x2 with scalar (wave-uniform) coeffs on a register pair
__device__ __forceinline__ void u3_pair(v2f& a0r, v2f& a0i, v2f& a1r, v2f& a1i, const CMat& U) {
    v2f n0r = U.m00r*a0r - U.m00i*a0i + U.m01r*a1r - U.m01i*a1i;
    v2f n0i = U.m00r*a0i + U.m00i*a0r + U.m01r*a1i + U.m01i*a1r;
    v2f n1r = U.m10r*a0r - U.m10i*a0i + U.m11r*a1r - U.m11i*a1i;
    v2f n1i = U.m10r*a0i + U.m10i*a0r + U.m11r*a1i + U.m11i*a1r;
    a0r = n0r; a0i = n0i; a1r = n1r; a1i = n1i;
}
// full complex 2x2 with per-component (v2f) coeffs
__device__ __forceinline__ void u3_pair_v(v2f& a0r, v2f& a0i, v2f& a1r, v2f& a1i,
    v2f u00r, v2f u00i, v2f u01r, v2f u01i, v2f u10r, v2f u10i, v2f u11r, v2f u11i) {
    v2f n0r = u00r*a0r - u00i*a0i + u01r*a1r - u01i*a1i;
    v2f n0i = u00r*a0i + u00i*a0r + u01r*a1i + u01i*a1r;
    v2f n1r = u10r*a0r - u10i*a0i + u11r*a1r - u11i*a1i;
    v2f n1i = u10r*a0i + u10i*a0r + u11r*a1i + u11i*a1r;
    a0r = n0r; a0i = n0i; a1r = n1r; a1i = n1i;
}
__device__ __forceinline__ void ry_pair(v2f& a0r, v2f& a0i, v2f& a1r, v2f& a1i,
                                        float c, float s) {
    v2f n0r = c*a0r - s*a1r;
    v2f n0i = c*a0i - s*a1i;
    v2f n1r = s*a0r + c*a1r;
    v2f n1i = s*a0i + c*a1i;
    a0r = n0r; a0i = n0i; a1r = n1r; a1i = n1i;
}

// generic lane-bit gate: per-lane diag (dr,di) and off-diag (orr,oii)
template<int P>
__device__ __forceinline__ void gate_lane(v2f (&Sr)[8], v2f (&Si)[8], int bpx32,
                                          float dr, float di, float orr, float oii) {
#pragma unroll
    for (int k = 0; k < 8; ++k) {
        const v2f mr = Sr[k], mi = Si[k];
        const v2f pr = partner2<P>(mr, bpx32);
        const v2f pi = partner2<P>(mi, bpx32);
        Sr[k] = dr*mr - di*mi + orr*pr - oii*pi;
        Si[k] = dr*mi + di*mr + orr*pi + oii*pr;
    }
}

// CRY: ctrl lane-bit PC, target lane-bit PT
template<int PC, int PT>
__device__ __forceinline__ void cry_lane(v2f (&Sr)[8], v2f (&Si)[8], int lane, int bpx32,
                                         float c, float s) {
    const bool ctrl = (lane >> PC) & 1;
    const float cl = ctrl ? c : 1.0f;
    const float sl = ctrl ? s : 0.0f;
    const bool hi = (lane >> PT) & 1;
    const float sgn = hi ? sl : -sl;
#pragma unroll
    for (int k = 0; k < 8; ++k) {
        const v2f pr = partner2<PT>(Sr[k], bpx32);
        const v2f pi = partner2<PT>(Si[k], bpx32);
        Sr[k] = cl * Sr[k] + sgn * pr;
        Si[k] = cl * Si[k] + sgn * pi;
    }
}

// fused U3+CRY: ctrl lane-bit PC selects matrix B (=RY*U3) vs A (=U3); target lane-bit PT
template<int PC, int PT>
__device__ __forceinline__ void fused_u3cry_lane(v2f (&Sr)[8], v2f (&Si)[8], int lane, int bpx32,
                                                 const CMat& A, const CMat& B) {
    const bool ctrl = (lane >> PC) & 1;
    const bool hi = (lane >> PT) & 1;
    const float d0r = ctrl ? B.m00r : A.m00r, d0i = ctrl ? B.m00i : A.m00i;
    const float d1r = ctrl ? B.m11r : A.m11r, d1i = ctrl ? B.m11i : A.m11i;
    const float o0r = ctrl ? B.m01r : A.m01r, o0i = ctrl ? B.m01i : A.m01i;
    const float o1r = ctrl ? B.m10r : A.m10r, o1i = ctrl ? B.m10i : A.m10i;
    const float dr  = hi ? d1r : d0r, di  = hi ? d1i : d0i;
    const float orr = hi ? o1r : o0r, oii = hi ? o1i : o0i;
    gate_lane<PT>(Sr, Si, bpx32, dr, di, orr, oii);
}

// fused U3+CRY with ctrl = k-bit0 (compile-time per k), target lane-bit P
template<int P>
__device__ __forceinline__ void fused_kparity(v2f (&Sr)[8], v2f (&Si)[8], int lane, int bpx32,
                                              const CMat& A, const CMat& B) {
    const bool hi = (lane >> P) & 1;
    const float dAr = hi ? A.m11r : A.m00r, dAi = hi ? A.m11i : A.m00i;
    const float oAr = hi ? A.m10r : A.m01r, oAi = hi ? A.m10i : A.m01i;
    const float dBr = hi ? B.m11r : B.m00r, dBi = hi ? B.m11i : B.m00i;
    const float oBr = hi ? B.m10r : B.m01r, oBi = hi ? B.m10i : B.m01i;
#pragma unroll
    for (int k = 0; k < 8; ++k) {
        const float dr  = (k & 1) ? dBr : dAr, di  = (k & 1) ? dBi : dAi;
        const float orr = (k & 1) ? oBr : oAr, oii = (k & 1) ? oBi : oAi;
        const v2f mr = Sr[k], mi = Si[k];
        const v2f pr = partner2<P>(mr, bpx32);
        const v2f pi = partner2<P>(mi, bpx32);
        Sr[k] = dr*mr - di*mi + orr*pr - oii*pi;
        Si[k] = dr*mi + di*mr + orr*pi + oii*pr;
    }
}

__device__ __forceinline__ void cmul(float& xr, float& xi, float br, float bi) {
    const float nr = xr*br - xi*bi;
    const float ni = xr*bi + xi*br;
    xr = nr; xi = ni;
}

__device__ __forceinline__ float wave_sum(float x, int bpx32) {
    x += dppf<0xB1>(x);
    x += dppf<0x4E>(x);
    x += swzf<0x101F>(x);
    x += dppf<0x128>(x);
    x += swzf<0x401F>(x);
    x += bperm(bpx32, x);
    return x;
}

// State layout per wave (one batch element per wave):
//   global index i[9:0], qubit q at bit p = 9-q.
//   lane = i[5:0] (qubits 4..9), k = i[8:6] (qubits 3,2,1 on k bits 0,1,2), comp j = i9 (qubit 0)
//
// Circuit executed (algebraically equal to reference):
//   init includes U3_0 (product-state fold); CRY_0 e=0..8; F0 = U3_1(0)*CRY_0(9);
//   Fq = CRY_1(q-1)*U3_1(q) for q=1..9; CRY_1(9); measure.
__global__ __launch_bounds__(256) void qsim(const float* __restrict__ in,
                                            const float* __restrict__ w,
                                            float* __restrict__ out, int B) {
    const int lane = threadIdx.x & 63;
    const int wave = threadIdx.x >> 6;
    int b = blockIdx.x * 4 + wave;
    b = __builtin_amdgcn_readfirstlane(b);
    if (b >= B) return;
    const int bpx32 = (lane ^ 32) << 2;

    // ===== stage 1: distributed trig =====
    // lanes 0..9: U3_0(q); 10..19: U3_1(q)=A_q; 20..29: CRY_0(e); 30..39: CRY_1(e);
    // 40..49: input amps (cos,sin of pi*x/2); 50..59: become B matrices in stage 3.
    float ang0 = 0.0f, ang1 = 0.0f, ang2 = 0.0f;
    if (lane < 20) {
        const int L = lane / 10, q = lane - L * 10;
        const int wi = L * 40 + q * 3;
        const float phi = w[wi], theta = w[wi + 1], omega = w[wi + 2];
        ang0 = 0.5f * theta;
        ang1 = 0.5f * (phi + omega);
        ang2 = 0.5f * (phi - omega);
    } else if (lane < 40) {
        const int g = lane - 20;
        const int L = g / 10, e = g - L * 10;
        ang0 = 0.5f * w[L * 40 + 30 + e];          // FIXED_W is all-zero
    } else if (lane < 50) {
        float x = in[b * NQ + (lane - 40)];
        x = fminf(fmaxf(x, 0.0f), 1.0f);
        ang0 = 0.5f * 3.14159265358979323846f * x;
    }
    const float ca = __cosf(ang0), sa = __sinf(ang0);
    const float cb = __cosf(ang1), sb = __sinf(ang1);
    const float cg = __cosf(ang2), sg = __sinf(ang2);
    float c0 =  ca * cb, c1 = -ca * sb;   // U00
    float c2 = -sa * cg, c3 = -sa * sg;   // U01
    float c4 =  sa * cg, c5 = -sa * sg;   // U10
    float c6 =  ca * cb, c7 =  ca * sb;   // U11
    if (lane >= 20) { c0 = ca; c1 = sa; } // CRY / input lanes: plain (cos, sin)

    // ===== stage 2: cross-lane gathers for derived coefficients =====
    const int srcA = ((lane - 40) & 63) * 4;  // lanes 40..49 -> U3_0 lanes 0..9; 50..59 -> U3_1 lanes 10..19
    const float a00r = bperm(srcA, c0), a00i = bperm(srcA, c1);
    const float a01r = bperm(srcA, c2), a01i = bperm(srcA, c3);
    const float a10r = bperm(srcA, c4), a10i = bperm(srcA, c5);
    const float a11r = bperm(srcA, c6), a11i = bperm(srcA, c7);
    const int srcC = ((lane - 21) & 63) * 4;  // lanes 50..59 -> CRY lanes 29..38 (CRY_0 e9, CRY_1 e0..8)
    const float ct = bperm(srcC, c0), st = bperm(srcC, c1);

    // ===== stage 3: derived coefficients =====
    // lanes 51..59: B_q = RY(th)*A_q (left);  lane 50: B_0 = A_0*RY(th) (right)
    const float BL00r = ct*a00r - st*a10r, BL00i = ct*a00i - st*a10i;
    const float BL01r = ct*a01r - st*a11r, BL01i = ct*a01i - st*a11i;
    const float BL10r = st*a00r + ct*a10r, BL10i = st*a00i + ct*a10i;
    const float BL11r = st*a01r + ct*a11r, BL11i = st*a01i + ct*a11i;
    const float BR00r = a00r*ct + a01r*st, BR00i = a00i*ct + a01i*st;
    const float BR01r = a01r*ct - a00r*st, BR01i = a01i*ct - a00i*st;
    const float BR10r = a10r*ct + a11r*st, BR10i = a10i*ct + a11i*st;
    const float BR11r = a11r*ct - a10r*st, BR11i = a11i*ct - a10i*st;
    const bool isR = (lane == 50);
    const float B00r = isR ? BR00r : BL00r, B00i = isR ? BR00i : BL00i;
    const float B01r = isR ? BR01r : BL01r, B01i = isR ? BR01i : BL01i;
    const float B10r = isR ? BR10r : BL10r, B10i = isR ? BR10i : BL10i;
    const float B11r = isR ? BR11r : BL11r, B11i = isR ? BR11i : BL11i;
    // lanes 40..49: transformed input amps t = U3_0(q) . (cos, sin)
    const float ti0r = a00r*c0 + a01r*c1, ti0i = a00i*c0 + a01i*c1;
    const float ti1r = a10r*c0 + a11r*c1, ti1i = a10i*c0 + a11i*c1;
    const bool isB = (lane >= 50);
    const bool isT = (lane >= 40) && (lane < 50);
    c0 = isB ? B00r : (isT ? ti0r : c0);
    c1 = isB ? B00i : (isT ? ti0i : c1);
    c2 = isB ? B01r : (isT ? ti1r : c2);
    c3 = isB ? B01i : (isT ? ti1i : c3);
    c4 = isB ? B10r : c4;
    c5 = isB ? B10i : c5;
    c6 = isB ? B11r : c6;
    c7 = isB ? B11i : c7;

    // ===== init: product state with U3_0 folded in =====
    float t0r[NQ], t0i[NQ], t1r[NQ], t1i[NQ];
#pragma unroll
    for (int q = 0; q < NQ; ++q) {
        t0r[q] = RL(c0, 40 + q); t0i[q] = RL(c1, 40 + q);
        t1r[q] = RL(c2, 40 + q); t1i[q] = RL(c3, 40 + q);
    }
    // lane-bit amplitude chain (qubit 9-j on lane bit j)
    float lr, li;
    {
        const bool j0 = lane & 1;
        lr = j0 ? t1r[9] : t0r[9];
        li = j0 ? t1i[9] : t0i[9];
#pragma unroll
        for (int j = 1; j < 6; ++j) {
            const int q = 9 - j;
            const bool bit = (lane >> j) & 1;
            cmul(lr, li, bit ? t1r[q] : t0r[q], bit ? t1i[q] : t0i[q]);
        }
    }
    v2f Sr[8], Si[8];
    const v2f T0r = {t0r[0], t1r[0]};
    const v2f T0i = {t0i[0], t1i[0]};
#pragma unroll
    for (int k = 0; k < 8; ++k) {
        float mr = (k & 4) ? t1r[1] : t0r[1];   // k bit2 = qubit1
        float mi = (k & 4) ? t1i[1] : t0i[1];
        cmul(mr, mi, (k & 2) ? t1r[2] : t0r[2], (k & 2) ? t1i[2] : t0i[2]);
        cmul(mr, mi, (k & 1) ? t1r[3] : t0r[3], (k & 1) ? t1i[3] : t0i[3]);
        cmul(mr, mi, lr, li);
        Sr[k] = mr * T0r - mi * T0i;
        Si[k] = mr * T0i + mi * T0r;
    }

    // ===== CRY_0 ring, e = 0..8 =====
    {   // e0: ctrl q0 (comp), tgt q1 (k bit2)
        const float c = RL(c0, 20), s = RL(c1, 20);
        const v2f cv = {1.0f, c};
        const v2f sv = {0.0f, s};
#pragma unroll
        for (int k0 = 0; k0 < 4; ++k0) {
            const int k1 = k0 | 4;
            v2f n0r = cv*Sr[k0] - sv*Sr[k1];
            v2f n0i = cv*Si[k0] - sv*Si[k1];
            v2f n1r = sv*Sr[k0] + cv*Sr[k1];
            v2f n1i = sv*Si[k0] + cv*Si[k1];
            Sr[k0] = n0r; Si[k0] = n0i; Sr[k1] = n1r; Si[k1] = n1i;
        }
    }
    {   // e1: ctrl q1 (k bit2), tgt q2 (k bit1)
        const float c = RL(c0, 21), s = RL(c1, 21);
        ry_pair(Sr[4], Si[4], Sr[6], Si[6], c, s);
        ry_pair(Sr[5], Si[5], Sr[7], Si[7], c, s);
    }
    {   // e2: ctrl q2 (k bit1), tgt q3 (k bit0)
        const float c = RL(c0, 22), s = RL(c1, 22);
        ry_pair(Sr[2], Si[2], Sr[3], Si[3], c, s);
        ry_pair(Sr[6], Si[6], Sr[7], Si[7], c, s);
    }
    {   // e3: ctrl q3 (k bit0), tgt q4 (lane bit5): only odd k
        const float c = RL(c0, 23), s = RL(c1, 23);
        const bool hi = (lane >> 5) & 1;
        const float sgn = hi ? s : -s;
#pragma unroll
        for (int k = 1; k < 8; k += 2) {
            const v2f pr = partner2<5>(Sr[k], bpx32);
            const v2f pi = partner2<5>(Si[k], bpx32);
            Sr[k] = c*Sr[k] + sgn*pr;
            Si[k] = c*Si[k] + sgn*pi;
        }
    }
    { const float c = RL(c0, 24), s = RL(c1, 24); cry_lane<5, 4>(Sr, Si, lane, bpx32, c, s); }
    { const float c = RL(c0, 25), s = RL(c1, 25); cry_lane<4, 3>(Sr, Si, lane, bpx32, c, s); }
    { const float c = RL(c0, 26), s = RL(c1, 26); cry_lane<3, 2>(Sr, Si, lane, bpx32, c, s); }
    { const float c = RL(c0, 27), s = RL(c1, 27); cry_lane<2, 1>(Sr, Si, lane, bpx32, c, s); }
    { const float c = RL(c0, 28), s = RL(c1, 28); cry_lane<1, 0>(Sr, Si, lane, bpx32, c, s); }

    // ===== F0 = U3_1(0) * CRY_0(9): ctrl q9 (lane bit0), tgt q0 (comp) =====
    {
        RLMAT(A, 10); RLMAT(Bm, 50);
        const bool ctrl = lane & 1;
        const float M00r = ctrl ? Bm.m00r : A.m00r, M00i = ctrl ? Bm.m00i : A.m00i;
        const float M01r = ctrl ? Bm.m01r : A.m01r, M01i = ctrl ? Bm.m01i : A.m01i;
        const float M10r = ctrl ? Bm.m10r : A.m10r, M10i = ctrl ? Bm.m10i : A.m10i;
        const float M11r = ctrl ? Bm.m11r : A.m11r, M11i = ctrl ? Bm.m11i : A.m11i;
        const v2f Dr = {M00r, M11r}, Di = {M00i, M11i};
        const v2f Or = {M01r, M10r}, Oi = {M01i, M10i};
#pragma unroll
        for (int k = 0; k < 8; ++k) {
            const v2f Ar = Sr[k], Ai = Si[k];
            const v2f Br = Ar.yx, Bi = Ai.yx;
            Sr[k] = Dr*Ar - Di*Ai + Or*Br - Oi*Bi;
            Si[k] = Dr*Ai + Di*Ar + Or*Bi + Oi*Br;
        }
    }
    // ===== F1 = CRY_1(0) * U3_1(1): ctrl q0 (comp), tgt q1 (k bit2) =====
    {
        RLMAT(A, 11); RLMAT(Bm, 51);
        const v2f u00r = {A.m00r, Bm.m00r}, u00i = {A.m00i, Bm.m00i};
        const v2f u01r = {A.m01r, Bm.m01r}, u01i = {A.m01i, Bm.m01i};
        const v2f u10r = {A.m10r, Bm.m10r}, u10i = {A.m10i, Bm.m10i};
        const v2f u11r = {A.m11r, Bm.m11r}, u11i = {A.m11i, Bm.m11i};
#pragma unroll
        for (int k0 = 0; k0 < 4; ++k0) {
            const int k1 = k0 | 4;
            u3_pair_v(Sr[k0], Si[k0], Sr[k1], Si[k1],
                      u00r, u00i, u01r, u01i, u10r, u10i, u11r, u11i);
        }
    }
    // ===== F2 = CRY_1(1) * U3_1(2): ctrl q1 (k bit2), tgt q2 (k bit1) =====
    {
        RLMAT(A, 12); RLMAT(Bm, 52);
        u3_pair(Sr[0], Si[0], Sr[2], Si[2], A);
        u3_pair(Sr[1], Si[1], Sr[3], Si[3], A);
        u3_pair(Sr[4], Si[4], Sr[6], Si[6], Bm);
        u3_pair(Sr[5], Si[5], Sr[7], Si[7], Bm);
    }
    // ===== F3 = CRY_1(2) * U3_1(3): ctrl q2 (k bit1), tgt q3 (k bit0) =====
    {
        RLMAT(A, 13); RLMAT(Bm, 53);
        u3_pair(Sr[0], Si[0], Sr[1], Si[1], A);
        u3_pair(Sr[4], Si[4], Sr[5], Si[5], A);
        u3_pair(Sr[2], Si[2], Sr[3], Si[3], Bm);
        u3_pair(Sr[6], Si[6], Sr[7], Si[7], Bm);
    }
    // ===== F4 = CRY_1(3) * U3_1(4): ctrl q3 (k bit0), tgt q4 (lane bit5) =====
    {
        RLMAT(A, 14); RLMAT(Bm, 54);
        fused_kparity<5>(Sr, Si, lane, bpx32, A, Bm);
    }
    // ===== F5..F9: ctrl/tgt lane bits =====
    { RLMAT(A, 15); RLMAT(Bm, 55); fused_u3cry_lane<5, 4>(Sr, Si, lane, bpx32, A, Bm); }
    { RLMAT(A, 16); RLMAT(Bm, 56); fused_u3cry_lane<4, 3>(Sr, Si, lane, bpx32, A, Bm); }
    { RLMAT(A, 17); RLMAT(Bm, 57); fused_u3cry_lane<3, 2>(Sr, Si, lane, bpx32, A, Bm); }
    { RLMAT(A, 18); RLMAT(Bm, 58); fused_u3cry_lane<2, 1>(Sr, Si, lane, bpx32, A, Bm); }
    { RLMAT(A, 19); RLMAT(Bm, 59); fused_u3cry_lane<1, 0>(Sr, Si, lane, bpx32, A, Bm); }
    // ===== CRY_1(9): ctrl q9 (lane bit0), tgt q0 (comp) =====
    {
        const float c = RL(c0, 39), s = RL(c1, 39);
        const bool ctrl = lane & 1;
        const float cl = ctrl ? c : 1.0f;
        const float sl = ctrl ? s : 0.0f;
        const v2f C2 = {cl, cl};
        const v2f S2 = {-sl, sl};
#pragma unroll
        for (int k = 0; k < 8; ++k) {
            const v2f Ar = Sr[k], Ai = Si[k];
            Sr[k] = C2*Ar + S2*Ar.yx;
            Si[k] = C2*Ai + S2*Ai.yx;
        }
    }

    // ===== measurement =====
    v2f P[8];
    float ptot = 0.0f;
#pragma unroll
    for (int k = 0; k < 8; ++k) {
        P[k] = Sr[k]*Sr[k] + Si[k]*Si[k];
        ptot += P[k].x + P[k].y;
    }
    float z[NQ];
    {
        float acc = 0.0f;
#pragma unroll
        for (int k = 0; k < 8; ++k) acc += P[k].x - P[k].y;
        z[0] = acc;
    }
#pragma unroll
    for (int q = 1; q <= 3; ++q) {
        const int kb = (q == 1) ? 2 : (q == 2) ? 1 : 0;
        float acc = 0.0f;
#pragma unroll
        for (int k = 0; k < 8; ++k) {
            const float pk = P[k].x + P[k].y;
            acc += ((k >> kb) & 1) ? -pk : pk;
        }
        z[q] = acc;
    }
#pragma unroll
    for (int q = 4; q < NQ; ++q) {
        const int p = 9 - q;
        z[q] = ((lane >> p) & 1) ? -ptot : ptot;
    }
#pragma unroll
    for (int q = 0; q < NQ; ++q) z[q] = wave_sum(z[q], bpx32);

    if (lane == 0) {
#pragma unroll
        for (int q = 0; q < NQ; ++q) out[b * NQ + q] = z[q];
    }
}

extern "C" void kernel_launch(void* const* d_in, const int* in_sizes, int n_in,
                              void* d_out, int out_size, void* d_ws, size_t ws_size,
                              hipStream_t stream) {
    const float* inputs  = (const float*)d_in[0];
    const float* weights = (const float*)d_in[1];
    float* out = (float*)d_out;
    const int B = in_sizes[0] / NQ;

    qsim<<<(B + 3) / 4, 256, 0, stream>>>(inputs, weights, out, B);
}